// Round 12
// baseline (155.440 us; speedup 1.0000x reference)
//
#include <hip/hip_runtime.h>

#define BB 8
#define NN 512
#define SS 96
#define HH 256
#define OUTD 4

typedef __attribute__((ext_vector_type(8))) short bf16x8;
typedef __attribute__((ext_vector_type(4))) float f32x4;

__device__ __forceinline__ unsigned short f2bf(float f) {
    unsigned int u = __float_as_uint(f);
    u = (u + 0x7FFFu + ((u >> 16) & 1u)) >> 16;   // RNE
    return (unsigned short)u;
}

// load 8 consecutive fp32 -> bf16x8 fragment (inline cvt)
__device__ __forceinline__ bf16x8 ldw8(const float* __restrict__ p) {
    float4 a = *(const float4*)p, b = *(const float4*)(p + 4);
    bf16x8 r;
    r[0] = (short)f2bf(a.x); r[1] = (short)f2bf(a.y);
    r[2] = (short)f2bf(a.z); r[3] = (short)f2bf(a.w);
    r[4] = (short)f2bf(b.x); r[5] = (short)f2bf(b.y);
    r[6] = (short)f2bf(b.z); r[7] = (short)f2bf(b.w);
    return r;
}

// ============================================================
// A tiles in LDS: bf16 [R][256], 16B-slot XOR swizzle slot' = slot ^ (row&7).
// W always fp32 global [NC][256] row-major, cvt inline.
// Wave w owns output cols [w*NCT*16, (w+1)*NCT*16).
// ============================================================

// multi-row-tile stage: NRT 16-row tiles, weight frags held in regs across tiles
template<int NRT, int NCT>
__device__ __forceinline__ void mfma_multi(
    const unsigned short* __restrict__ Asw,      // [NRT*16][256] swizzled
    const float* __restrict__ Wf,
    int lane, int wave, f32x4 acc[NRT][NCT])
{
    const int row = lane & 15, kq = lane >> 4;
    #pragma unroll
    for (int rt = 0; rt < NRT; ++rt)
        #pragma unroll
        for (int ct = 0; ct < NCT; ++ct) acc[rt][ct] = (f32x4){0.f, 0.f, 0.f, 0.f};
    #pragma unroll
    for (int kt = 0; kt < 8; ++kt) {
        bf16x8 w[NCT];
        #pragma unroll
        for (int ct = 0; ct < NCT; ++ct)
            w[ct] = ldw8(Wf + (size_t)((wave * NCT + ct) * 16 + row) * 256 + kt * 32 + kq * 8);
        #pragma unroll
        for (int rt = 0; rt < NRT; ++rt) {
            bf16x8 a = *(const bf16x8*)(Asw + (rt * 16 + row) * 256 +
                                        (((kt * 4 + kq) ^ (row & 7)) << 3));
            #pragma unroll
            for (int ct = 0; ct < NCT; ++ct)
                acc[rt][ct] = __builtin_amdgcn_mfma_f32_16x16x32_bf16(a, w[ct], acc[rt][ct], 0, 0, 0);
        }
    }
}

// epilogue tile -> LDS bf16 swizzled (16-row tile at row offset rbase)
template<bool RELU>
__device__ __forceinline__ void epi_tile(
    unsigned short* __restrict__ OutSw, int rbase, const float* __restrict__ bias,
    int C16, int lane, const f32x4 acc)     // C16 = base col of this 16-tile
{
    const int col0 = lane & 15, rq = lane >> 4;
    const int C = C16 + col0;
    const float bb = bias[C];
    const int slot = C >> 3, within = C & 7;
    #pragma unroll
    for (int r = 0; r < 4; ++r) {
        const int R = rbase + rq * 4 + r;
        float v = acc[r] + bb;
        if (RELU) v = fmaxf(v, 0.f);
        OutSw[R * 256 + ((slot ^ (R & 7)) << 3) + within] = f2bf(v);
    }
}

// stage fp32 global [16][256] -> LDS bf16 swizzled (512 threads)
__device__ __forceinline__ void stage16(
    const float* __restrict__ Ag, unsigned short* __restrict__ Asw, int tid)
{
    #pragma unroll
    for (int ii = 0; ii < 2; ++ii) {
        int i = tid + ii * 512;
        int row = i >> 6, c4 = i & 63;
        float4 v = ((const float4*)(Ag + (size_t)row * 256))[c4];
        int col = c4 * 4;
        int slot = col >> 3, half = (col >> 2) & 1;
        ushort4 o;
        o.x = f2bf(v.x); o.y = f2bf(v.y); o.z = f2bf(v.z); o.w = f2bf(v.w);
        *(ushort4*)(Asw + row * 256 + ((slot ^ (row & 7)) << 3) + half * 4) = o;
    }
}

// ============================================================
// ONE kernel, ONE dispatch, NO workspace.
// grid = 256 blocks (b = blk>>5, n0 = (blk&31)*16) x 512 thr (8 waves).
// Each block redundantly computes its batch's k/vT in LDS, then its
// 16-row q-chain, attention (head = wave), MLP, broadcast.
// ============================================================
__global__ __launch_bounds__(512, 1) void k_all(
    const float* __restrict__ spatial, const float* __restrict__ temporal,
    const float* __restrict__ Ws, const float* __restrict__ bs,
    const float* __restrict__ Wt, const float* __restrict__ bt,
    const float* __restrict__ Win, const float* __restrict__ bin,
    const float* __restrict__ Wao, const float* __restrict__ bao,
    const float* __restrict__ W1, const float* __restrict__ b1,
    const float* __restrict__ Wo1, const float* __restrict__ bo1,
    const float* __restrict__ Wo2, const float* __restrict__ bo2,
    float* __restrict__ out)
{
    __shared__ __align__(16) unsigned short TPB[96 * 256];   // 48 KB: tp, later q-phase bufs
    __shared__ __align__(16) unsigned short KB[96 * 256];    // 48 KB: TIN -> K -> P
    __shared__ __align__(16) unsigned short VTB[256 * 104];  // 52 KB: vT [256][104]

    const int tid = threadIdx.x, lane = tid & 63, wave = tid >> 6;
    const int cl = lane & 15, kq = lane >> 4;
    const int b = blockIdx.x >> 5;
    const int n0 = (blockIdx.x & 31) * 16;
    const float scale = 0.17677669529663687f;  // 1/sqrt(32)

    // q-phase aliases inside TPB (TP dead by then)
    unsigned short* A0  = TPB;             // [16][256]
    unsigned short* MID = TPB + 4096;
    unsigned short* Q   = TPB + 8192;
    float* H2 = (float*)(TPB + 12288);     // [16][128] f32
    float* yv = (float*)(TPB + 16384);     // [16][4]

    // ---- S1: stage temporal[b] (96x256) -> KB as TIN ----
    {
        const float* Tg = temporal + (size_t)b * SS * HH;
        #pragma unroll
        for (int ii = 0; ii < 12; ++ii) {
            int i = tid + ii * 512;
            int row = i >> 6, c4 = i & 63;
            float4 v = ((const float4*)(Tg + (size_t)row * 256))[c4];
            int col = c4 * 4, slot = col >> 3, half = (col >> 2) & 1;
            ushort4 o;
            o.x = f2bf(v.x); o.y = f2bf(v.y); o.z = f2bf(v.z); o.w = f2bf(v.w);
            *(ushort4*)(KB + row * 256 + ((slot ^ (row & 7)) << 3) + half * 4) = o;
        }
    }
    __syncthreads();

    // ---- S2: TP = TIN @ Wt.T + bt -> TPB (96 rows) ----
    {
        f32x4 acc[6][2];
        mfma_multi<6, 2>(KB, Wt, lane, wave, acc);
        #pragma unroll
        for (int rt = 0; rt < 6; ++rt)
            #pragma unroll
            for (int ct = 0; ct < 2; ++ct)
                epi_tile<false>(TPB, rt * 16, bt, (wave * 2 + ct) * 16, lane, acc[rt][ct]);
    }
    __syncthreads();

    // ---- S3: vT = (TP @ Wv.T + bv) transposed -> VTB [256][104] ----
    {
        f32x4 acc[6][2];
        mfma_multi<6, 2>(TPB, Win + (size_t)512 * 256, lane, wave, acc);
        const int rq = lane >> 4;
        #pragma unroll
        for (int ct = 0; ct < 2; ++ct) {
            const int C = (wave * 2 + ct) * 16 + cl;
            const float bv = bin[512 + C];
            #pragma unroll
            for (int rt = 0; rt < 6; ++rt)
                #pragma unroll
                for (int r = 0; r < 4; ++r)
                    VTB[C * 104 + rt * 16 + rq * 4 + r] = f2bf(acc[rt][ct][r] + bv);
        }
    }
    // ---- S4: K = TP @ Wk.T + bk -> KB (overwrites TIN; TIN dead since S2 barrier) ----
    {
        f32x4 acc[6][2];
        mfma_multi<6, 2>(TPB, Win + (size_t)256 * 256, lane, wave, acc);
        #pragma unroll
        for (int rt = 0; rt < 6; ++rt)
            #pragma unroll
            for (int ct = 0; ct < 2; ++ct)
                epi_tile<false>(KB, rt * 16, bin + 256, (wave * 2 + ct) * 16, lane, acc[rt][ct]);
    }
    __syncthreads();

    // ---- S5: stage spatial rows n0.. -> A0 (TPB; TP dead) ----
    stage16(spatial + (size_t)(b * NN + n0) * 256, A0, tid);
    __syncthreads();

    // ---- S6: SP = A0 @ Ws.T + bs -> MID ----
    {
        f32x4 acc[1][2];
        mfma_multi<1, 2>(A0, Ws, lane, wave, acc);
        #pragma unroll
        for (int ct = 0; ct < 2; ++ct)
            epi_tile<false>(MID, 0, bs, (wave * 2 + ct) * 16, lane, acc[0][ct]);
    }
    __syncthreads();

    // ---- S7: Q = MID @ Wq.T + bq -> Q (wave-private cols; no barrier) ----
    {
        f32x4 acc[1][2];
        mfma_multi<1, 2>(MID, Win, lane, wave, acc);
        #pragma unroll
        for (int ct = 0; ct < 2; ++ct)
            epi_tile<false>(Q, 0, bin, (wave * 2 + ct) * 16, lane, acc[0][ct]);
    }

    // ---- S8: attention, head = wave; Q/K from LDS ----
    f32x4 l[6];
    {
        const int h = wave;
        const int slotq = h * 4 + kq;
        bf16x8 aq = *(const bf16x8*)(Q + cl * 256 + ((slotq ^ (cl & 7)) << 3));
        #pragma unroll
        for (int t = 0; t < 6; ++t) {
            const int R = t * 16 + cl;
            bf16x8 bk = *(const bf16x8*)(KB + R * 256 + ((slotq ^ (R & 7)) << 3));
            l[t] = __builtin_amdgcn_mfma_f32_16x16x32_bf16(aq, bk, (f32x4){0.f,0.f,0.f,0.f}, 0, 0, 0);
        }
    }
    __syncthreads();   // all K reads done before P overwrites KB

    {
        const int h = wave;
        float pr[6][4];
        float sum[4] = {0.f, 0.f, 0.f, 0.f};
        #pragma unroll
        for (int t = 0; t < 6; ++t)
            #pragma unroll
            for (int r = 0; r < 4; ++r) {
                float p = __expf(l[t][r] * scale);   // logits O(0.01): no max needed
                pr[t][r] = p; sum[r] += p;
            }
        #pragma unroll
        for (int r = 0; r < 4; ++r) {
            float s = sum[r];
            s += __shfl_xor(s, 1); s += __shfl_xor(s, 2);
            s += __shfl_xor(s, 4); s += __shfl_xor(s, 8);
            sum[r] = 1.0f / s;
        }
        unsigned short* Pw = KB + wave * 16 * 104;    // wave-private
        #pragma unroll
        for (int t = 0; t < 6; ++t)
            #pragma unroll
            for (int r = 0; r < 4; ++r)
                Pw[(kq * 4 + r) * 104 + t * 16 + cl] = f2bf(pr[t][r] * sum[r]);
        // PV: ctx [16 n][32 d] from P (LDS) x vT (LDS)
        f32x4 c0 = (f32x4){0.f,0.f,0.f,0.f}, c1 = (f32x4){0.f,0.f,0.f,0.f};
        #pragma unroll
        for (int ks = 0; ks < 3; ++ks) {
            bf16x8 pa = *(const bf16x8*)(Pw + cl * 104 + ks * 32 + kq * 8);
            bf16x8 v0 = *(const bf16x8*)(VTB + (h * 32 + cl) * 104 + ks * 32 + kq * 8);
            bf16x8 v1 = *(const bf16x8*)(VTB + (h * 32 + 16 + cl) * 104 + ks * 32 + kq * 8);
            c0 = __builtin_amdgcn_mfma_f32_16x16x32_bf16(pa, v0, c0, 0, 0, 0);
            c1 = __builtin_amdgcn_mfma_f32_16x16x32_bf16(pa, v1, c1, 0, 0, 0);
        }
        // ctx -> A0 (swizzled), cols h*32..h*32+31 (A0 dead since S6 barrier)
        #pragma unroll
        for (int dt = 0; dt < 2; ++dt) {
            const f32x4 cc = dt ? c1 : c0;
            const int C = h * 32 + dt * 16 + cl;
            const int slot = C >> 3, within = C & 7;
            #pragma unroll
            for (int r = 0; r < 4; ++r) {
                const int R = kq * 4 + r;
                A0[R * 256 + ((slot ^ (R & 7)) << 3) + within] = f2bf(cc[r]);
            }
        }
    }
    __syncthreads();

    // ---- S10: attended = ctx @ Wao.T + bao -> MID ----
    {
        f32x4 acc[1][2];
        mfma_multi<1, 2>(A0, Wao, lane, wave, acc);
        #pragma unroll
        for (int ct = 0; ct < 2; ++ct)
            epi_tile<false>(MID, 0, bao, (wave * 2 + ct) * 16, lane, acc[0][ct]);
    }
    __syncthreads();
    // ---- S11: fused = relu(attended @ W1.T + b1) -> A0 ----
    {
        f32x4 acc[1][2];
        mfma_multi<1, 2>(MID, W1, lane, wave, acc);
        #pragma unroll
        for (int ct = 0; ct < 2; ++ct)
            epi_tile<true>(A0, 0, b1, (wave * 2 + ct) * 16, lane, acc[0][ct]);
    }
    __syncthreads();
    // ---- S12: h2 = relu(fused @ Wo1.T + bo1) -> H2 fp32 [16][128] ----
    {
        f32x4 acc[1][1];
        mfma_multi<1, 1>(A0, Wo1, lane, wave, acc);
        const int rq = lane >> 4;
        const int C = wave * 16 + cl;
        const float bb = bo1[C];
        #pragma unroll
        for (int r = 0; r < 4; ++r)
            H2[(rq * 4 + r) * 128 + C] = fmaxf(acc[0][0][r] + bb, 0.f);
    }
    __syncthreads();
    // ---- S13: y = h2 @ Wo2.T + bo2 ----
    if (tid < 64) {
        int r = tid >> 2, o = tid & 3;
        float a = 0.f;
        const float4* w4 = (const float4*)(Wo2 + (size_t)o * 128);
        const float4* h4 = (const float4*)(H2 + r * 128);
        for (int kk = 0; kk < 32; ++kk) {
            float4 w = w4[kk], hv = h4[kk];
            a += hv.x * w.x + hv.y * w.y + hv.z * w.z + hv.w * w.w;
        }
        yv[r * 4 + o] = a + bo2[o];
    }
    __syncthreads();
    // ---- S14: broadcast out[b][s][n0+r][:] = y[r] ----
    #pragma unroll
    for (int ii = 0; ii < 3; ++ii) {
        int i = tid + ii * 512;
        int s = i >> 4;
        int r = i & 15;
        *(float4*)(out + ((size_t)(b * SS + s) * NN + (n0 + r)) * OUTD) =
            *(const float4*)(yv + r * 4);
    }
}

extern "C" void kernel_launch(void* const* d_in, const int* in_sizes, int n_in,
                              void* d_out, int out_size, void* d_ws, size_t ws_size,
                              hipStream_t stream) {
    const float* spatial  = (const float*)d_in[0];
    const float* temporal = (const float*)d_in[1];
    const float* Ws  = (const float*)d_in[2];
    const float* bs  = (const float*)d_in[3];
    const float* Wt  = (const float*)d_in[4];
    const float* bt  = (const float*)d_in[5];
    const float* Win = (const float*)d_in[6];
    const float* bin = (const float*)d_in[7];
    const float* Wao = (const float*)d_in[8];
    const float* bao = (const float*)d_in[9];
    const float* W1  = (const float*)d_in[10];
    const float* b1  = (const float*)d_in[11];
    const float* Wo1 = (const float*)d_in[12];
    const float* bo1 = (const float*)d_in[13];
    const float* Wo2 = (const float*)d_in[14];
    const float* bo2 = (const float*)d_in[15];
    float* out = (float*)d_out;

    hipLaunchKernelGGL(k_all, dim3(256), dim3(512), 0, stream,
                       spatial, temporal, Ws, bs, Wt, bt, Win, bin,
                       Wao, bao, W1, b1, Wo1, bo1, Wo2, bo2, out);
}